// Round 3
// baseline (454.769 us; speedup 1.0000x reference)
//
#include <hip/hip_runtime.h>
#include <hip/hip_bf16.h>

// Problem constants (MoEAdaptorLayer_111669150283)
#define BATCH   512
#define LSEQ    50
#define DIN     768
#define DOUT    300
#define NEXP    8
#define NTOK    (BATCH * LSEQ)      // 25600

typedef __bf16 bf16_t;
typedef __attribute__((ext_vector_type(8))) __bf16 bf16x8;
typedef __attribute__((ext_vector_type(4))) float f32x4;

// async global->LDS, 16 B per lane, dst = wave-uniform base + lane*16
#define GLDS16(g, l) __builtin_amdgcn_global_load_lds( \
    (__attribute__((address_space(1))) void*)(g), \
    (__attribute__((address_space(3))) void*)(l), 16, 0, 0)

static __device__ __forceinline__ unsigned short f2bf(float f) {
    unsigned u = __float_as_uint(f);
    u = (u + 0x7fff + ((u >> 16) & 1)) >> 16;   // round-to-nearest-even
    return (unsigned short)u;
}

// ---------------------------------------------------------------------------
// Kernel 1 (fused): xb = bf16(x)  AND  gates = softmax(x @ w_gate).
// One wave per token. Lane j owns floats [4j..4j+3] + 256*k, k=0..2 (float4).
// wg rows are read as float4 pairs (L1-resident, 24 KB total).
// ---------------------------------------------------------------------------
__global__ __launch_bounds__(256) void cvt_gates_kernel(
    const float* __restrict__ x, const float* __restrict__ wg,
    unsigned short* __restrict__ xb, float* __restrict__ gates)
{
    int t    = blockIdx.x * 4 + (threadIdx.x >> 6);
    int lane = threadIdx.x & 63;
    const float4* xr = (const float4*)(x + (size_t)t * DIN);   // 192 float4/row
    ushort4* xo = (ushort4*)(xb + (size_t)t * DIN);

    float acc[NEXP];
    #pragma unroll
    for (int e = 0; e < NEXP; e++) acc[e] = 0.0f;

    #pragma unroll
    for (int k = 0; k < 3; ++k) {
        int i4 = lane + 64 * k;            // float4 index; i = 4*i4
        float4 v = xr[i4];
        ushort4 u;
        u.x = f2bf(v.x); u.y = f2bf(v.y); u.z = f2bf(v.z); u.w = f2bf(v.w);
        xo[i4] = u;
        const float4* wr = (const float4*)(wg + (size_t)i4 * 4 * NEXP);
        float xs[4] = {v.x, v.y, v.z, v.w};
        #pragma unroll
        for (int s = 0; s < 4; ++s) {
            float4 w0 = wr[2 * s];
            float4 w1 = wr[2 * s + 1];
            float xv = xs[s];
            acc[0] += xv * w0.x; acc[1] += xv * w0.y;
            acc[2] += xv * w0.z; acc[3] += xv * w0.w;
            acc[4] += xv * w1.x; acc[5] += xv * w1.y;
            acc[6] += xv * w1.z; acc[7] += xv * w1.w;
        }
    }
    #pragma unroll
    for (int e = 0; e < NEXP; e++) {
        #pragma unroll
        for (int m = 32; m > 0; m >>= 1) acc[e] += __shfl_xor(acc[e], m, 64);
    }
    float mx = acc[0];
    #pragma unroll
    for (int e = 1; e < NEXP; e++) mx = fmaxf(mx, acc[e]);
    float ex[NEXP]; float s = 0.0f;
    #pragma unroll
    for (int e = 0; e < NEXP; e++) { ex[e] = __expf(acc[e] - mx); s += ex[e]; }
    float inv = 1.0f / s;
    if (lane == 0) {
        #pragma unroll
        for (int e = 0; e < NEXP; e++) gates[(size_t)t * NEXP + e] = ex[e] * inv;
    }
}

// ---------------------------------------------------------------------------
// Kernel 2: bw[l,e,o] = sum_i bias[e,l,i] * W[e,o,i]  — float4 loads
// ---------------------------------------------------------------------------
__global__ __launch_bounds__(256) void bw_kernel(
    const float* __restrict__ bias, const float* __restrict__ W,
    float* __restrict__ bw)
{
    int wave = blockIdx.x * 4 + (threadIdx.x >> 6);
    int lane = threadIdx.x & 63;
    int l   = wave / (NEXP * DOUT);
    int rem = wave % (NEXP * DOUT);
    int e   = rem / DOUT;
    int o   = rem % DOUT;

    const float4* br = (const float4*)(bias + ((size_t)e * LSEQ + l) * DIN);
    const float4* wr = (const float4*)(W    + ((size_t)e * DOUT + o) * DIN);
    float acc = 0.0f;
    #pragma unroll
    for (int k = 0; k < 3; ++k) {
        int i4 = lane + 64 * k;
        float4 b = br[i4], w = wr[i4];
        acc += b.x * w.x + b.y * w.y + b.z * w.z + b.w * w.w;
    }
    #pragma unroll
    for (int m = 32; m > 0; m >>= 1) acc += __shfl_xor(acc, m, 64);
    if (lane == 0) bw[((size_t)l * NEXP + e) * DOUT + o] = acc;
}

// ---------------------------------------------------------------------------
// Kernel 3: fp32 -> bf16 conversion for W
// ---------------------------------------------------------------------------
__global__ __launch_bounds__(256) void cvt_bf16_kernel(
    const float* __restrict__ in, unsigned short* __restrict__ out, int n4)
{
    int i = blockIdx.x * 256 + threadIdx.x;
    if (i >= n4) return;
    float4 v = ((const float4*)in)[i];
    ushort4 u;
    u.x = f2bf(v.x); u.y = f2bf(v.y); u.z = f2bf(v.z); u.w = f2bf(v.w);
    ((ushort4*)out)[i] = u;
}

// ---------------------------------------------------------------------------
// Kernel 4: MFMA main GEMM + fused gate-weighted expert reduction.
// Block tile: 128 tokens x 256 cols (8 experts x 32 outputs). 4 waves.
// Wave w: token rows 32w..32w+31 (2 row-frags) x all 16 col-frags.
// Col n = 16f + m maps to expert n>>5, output o0 + (n&31); lane (m,q) holds
// experts 0..7 for outputs o0+m and o0+16+m -> expert reduction lane-local.
// LDS XOR-swizzle at 16B-chunk granularity via permuted global src addrs.
// ---------------------------------------------------------------------------
#define GTM 128            // tokens per block
#define GNO 32             // outputs per block
#define GNC 256            // cols = NEXP * GNO
#define GBK 32             // k per iteration (64 B per row)
#define GKIT (DIN / GBK)   // 24

__global__ __launch_bounds__(256) void moe_mfma_kernel(
    const bf16_t* __restrict__ xb, const bf16_t* __restrict__ wb,
    const float* __restrict__ gates, const float* __restrict__ bw,
    float* __restrict__ out)
{
    __shared__ bf16x8 XsV[GTM * GBK / 8];   //  8 KB
    __shared__ bf16x8 WsV[GNC * GBK / 8];   // 16 KB
    char* Xs = (char*)XsV;
    char* Ws = (char*)WsV;

    const int tid  = threadIdx.x;
    const int w    = tid >> 6;
    const int lane = tid & 63;
    const int o0   = blockIdx.x * GNO;
    const int t0   = blockIdx.y * GTM;

    const int srow4 = lane >> 2;                          // 0..15
    const int c16   = 16 * ((lane & 3) ^ ((lane >> 4) & 3));

    // X staging: wave w covers rows 32w..32w+31 in 2 instrs
    const char* xg0 = (const char*)xb + (size_t)(t0 + 32 * w + srow4) * (DIN * 2) + c16;
    const char* xg1 = xg0 + (size_t)16 * (DIN * 2);
    char* xl = Xs + 2048 * w;

    // W staging: wave w covers col rows 64w..64w+63 in 4 instrs
    const char* wgp[4];
    #pragma unroll
    for (int j = 0; j < 4; ++j) {
        int n = 64 * w + 16 * j + srow4;
        int e = n >> 5;
        int o = o0 + (n & 31); if (o >= DOUT) o = DOUT - 1;   // clamp; unused cols guarded in epilogue
        wgp[j] = (const char*)wb + (size_t)(e * DOUT + o) * (DIN * 2) + c16;
    }
    char* wl = Ws + 4096 * w;

    // fragment read offsets (swizzled)
    const int m = lane & 15, q = lane >> 4;
    const int swz  = (m >> 2) & 3;
    const int aoff0 = 64 * (32 * w + m) + 16 * (q ^ swz);
    const int aoff1 = aoff0 + 1024;
    const int boff  = 64 * m + 16 * (q ^ swz);

    f32x4 acc[2][16] = {};

    for (int it = 0; it < GKIT; ++it) {
        GLDS16(xg0, xl);
        GLDS16(xg1, xl + 1024);
        #pragma unroll
        for (int j = 0; j < 4; ++j) GLDS16(wgp[j], wl + 1024 * j);
        xg0 += 64; xg1 += 64;
        #pragma unroll
        for (int j = 0; j < 4; ++j) wgp[j] += 64;
        __syncthreads();

        bf16x8 a0 = *(const bf16x8*)(Xs + aoff0);
        bf16x8 a1 = *(const bf16x8*)(Xs + aoff1);
        #pragma unroll
        for (int f = 0; f < 16; ++f) {
            bf16x8 b = *(const bf16x8*)(Ws + boff + 1024 * f);
            acc[0][f] = __builtin_amdgcn_mfma_f32_16x16x32_bf16(a0, b, acc[0][f], 0, 0, 0);
            acc[1][f] = __builtin_amdgcn_mfma_f32_16x16x32_bf16(a1, b, acc[1][f], 0, 0, 0);
        }
        __syncthreads();
    }

    // epilogue: out[t,o] = sum_e g[t,e] * (acc - bw[l,e,o])
    #pragma unroll
    for (int mi = 0; mi < 2; ++mi) {
        #pragma unroll
        for (int r = 0; r < 4; ++r) {
            int t = t0 + 32 * w + 16 * mi + 4 * q + r;
            int l = t % LSEQ;
            float4 g0 = *(const float4*)(gates + (size_t)t * NEXP);
            float4 g1 = *(const float4*)(gates + (size_t)t * NEXP + 4);
            float ga[8] = {g0.x, g0.y, g0.z, g0.w, g1.x, g1.y, g1.z, g1.w};
            #pragma unroll
            for (int oh = 0; oh < 2; ++oh) {
                int o = o0 + 16 * oh + m;
                if (o < DOUT) {
                    const float* bp = bw + (size_t)l * NEXP * DOUT + o;
                    float s = 0.0f;
                    #pragma unroll
                    for (int e = 0; e < NEXP; ++e)
                        s += ga[e] * (acc[mi][2 * e + oh][r] - bp[e * DOUT]);
                    out[(size_t)t * DOUT + o] = s;
                }
            }
        }
    }
}

// ---------------------------------------------------------------------------
// Fallback fp32 path (verified round 1) — only if ws too small for bf16 bufs.
// ---------------------------------------------------------------------------
__global__ __launch_bounds__(256) void gates_kernel(
    const float* __restrict__ x, const float* __restrict__ wg,
    float* __restrict__ gates)
{
    int t    = blockIdx.x * 4 + (threadIdx.x >> 6);
    int lane = threadIdx.x & 63;
    const float* xr = x + (size_t)t * DIN;
    float acc[NEXP];
    #pragma unroll
    for (int e = 0; e < NEXP; e++) acc[e] = 0.0f;
    for (int i = lane; i < DIN; i += 64) {
        float xv = xr[i];
        const float* wr = wg + (size_t)i * NEXP;
        #pragma unroll
        for (int e = 0; e < NEXP; e++) acc[e] += xv * wr[e];
    }
    #pragma unroll
    for (int e = 0; e < NEXP; e++) {
        #pragma unroll
        for (int m = 32; m > 0; m >>= 1) acc[e] += __shfl_xor(acc[e], m, 64);
    }
    float mx = acc[0];
    #pragma unroll
    for (int e = 1; e < NEXP; e++) mx = fmaxf(mx, acc[e]);
    float ex[NEXP]; float s = 0.0f;
    #pragma unroll
    for (int e = 0; e < NEXP; e++) { ex[e] = __expf(acc[e] - mx); s += ex[e]; }
    float inv = 1.0f / s;
    if (lane == 0) {
        #pragma unroll
        for (int e = 0; e < NEXP; e++) gates[(size_t)t * NEXP + e] = ex[e] * inv;
    }
}

#define TM  64
#define TO  16
#define KT  32
#define KTP 36

__global__ __launch_bounds__(256) void moe_main_kernel(
    const float* __restrict__ x, const float* __restrict__ W,
    const float* __restrict__ gates, const float* __restrict__ bw,
    float* __restrict__ out)
{
    __shared__ float Xs[TM][KTP];
    __shared__ float Wls[128][KTP];
    const int tid = threadIdx.x;
    const int t0 = blockIdx.x * TM;
    const int o0 = blockIdx.y * TO;
    const int cg = tid & 15;
    const int tg = tid >> 4;
    const int lrow = tid >> 3;
    const int lk4  = (tid & 7) * 4;
    float acc[4][NEXP];
    #pragma unroll
    for (int i = 0; i < 4; i++)
        #pragma unroll
        for (int j = 0; j < NEXP; j++) acc[i][j] = 0.0f;
    for (int k0 = 0; k0 < DIN; k0 += KT) {
        #pragma unroll
        for (int r = 0; r < 2; r++) {
            int row = lrow + 32 * r;
            float4 v = *(const float4*)&x[((size_t)(t0 + row)) * DIN + k0 + lk4];
            *(float4*)&Xs[row][lk4] = v;
        }
        #pragma unroll
        for (int r = 0; r < 4; r++) {
            int nl = lrow + 32 * r;
            int e  = nl >> 4;
            int o  = o0 + (nl & 15);
            float4 v;
            if (o < DOUT)
                v = *(const float4*)&W[((size_t)e * DOUT + o) * DIN + k0 + lk4];
            else
                v = make_float4(0.f, 0.f, 0.f, 0.f);
            *(float4*)&Wls[nl][lk4] = v;
        }
        __syncthreads();
        #pragma unroll
        for (int k4 = 0; k4 < KT; k4 += 4) {
            float4 xa[4], wb4[NEXP];
            #pragma unroll
            for (int i = 0; i < 4; i++)
                xa[i] = *(const float4*)&Xs[tg + 16 * i][k4];
            #pragma unroll
            for (int j = 0; j < NEXP; j++)
                wb4[j] = *(const float4*)&Wls[cg + 16 * j][k4];
            #pragma unroll
            for (int i = 0; i < 4; i++)
                #pragma unroll
                for (int j = 0; j < NEXP; j++) {
                    acc[i][j] += xa[i].x * wb4[j].x;
                    acc[i][j] += xa[i].y * wb4[j].y;
                    acc[i][j] += xa[i].z * wb4[j].z;
                    acc[i][j] += xa[i].w * wb4[j].w;
                }
        }
        __syncthreads();
    }
    const int o = o0 + cg;
    if (o < DOUT) {
        #pragma unroll
        for (int i = 0; i < 4; i++) {
            int t = t0 + tg + 16 * i;
            int l = t % LSEQ;
            float s = 0.0f;
            #pragma unroll
            for (int j = 0; j < NEXP; j++) {
                float g = gates[(size_t)t * NEXP + j];
                s += g * (acc[i][j] - bw[((size_t)l * NEXP + j) * DOUT + o]);
            }
            out[(size_t)t * DOUT + o] = s;
        }
    }
}

// ---------------------------------------------------------------------------
extern "C" void kernel_launch(void* const* d_in, const int* in_sizes, int n_in,
                              void* d_out, int out_size, void* d_ws, size_t ws_size,
                              hipStream_t stream) {
    const float* x     = (const float*)d_in[0];   // [512,50,768]
    const float* wgate = (const float*)d_in[1];   // [768,8]
    const float* ew    = (const float*)d_in[2];   // [8,300,768]
    const float* ebias = (const float*)d_in[3];   // [8,50,768]
    float* out = (float*)d_out;                   // [512,50,300]

    // ws layout: gates | bw | xb (bf16) | wb (bf16)
    const size_t n_gates = (size_t)NTOK * NEXP;           // 204800 f32
    const size_t n_bw    = (size_t)LSEQ * NEXP * DOUT;    // 120000 f32
    const size_t n_x     = (size_t)NTOK * DIN;            // 19,660,800
    const size_t n_w     = (size_t)NEXP * DOUT * DIN;     // 1,843,200

    float* gates = (float*)d_ws;
    float* bw    = gates + n_gates;
    bf16_t* xb   = (bf16_t*)(bw + n_bw);
    bf16_t* wbuf = xb + n_x;

    const size_t need = (n_gates + n_bw) * 4 + (n_x + n_w) * 2;

    bw_kernel<<<(LSEQ * NEXP * DOUT) / 4, 256, 0, stream>>>(ebias, ew, bw);

    if (ws_size >= need) {
        cvt_gates_kernel<<<NTOK / 4, 256, 0, stream>>>(
            x, wgate, (unsigned short*)xb, gates);
        cvt_bf16_kernel<<<(int)(n_w / 4 + 255) / 256, 256, 0, stream>>>(
            ew, (unsigned short*)wbuf, (int)(n_w / 4));
        dim3 grid((DOUT + GNO - 1) / GNO, NTOK / GTM);   // 10 x 200
        moe_mfma_kernel<<<grid, 256, 0, stream>>>(xb, wbuf, gates, bw, out);
    } else {
        gates_kernel<<<NTOK / 4, 256, 0, stream>>>(x, wgate, gates);
        dim3 grid(NTOK / TM, (DOUT + TO - 1) / TO);      // 400 x 19
        moe_main_kernel<<<grid, 256, 0, stream>>>(x, ew, gates, bw, out);
    }
}

// Round 4
// 346.905 us; speedup vs baseline: 1.3109x; 1.3109x over previous
//
#include <hip/hip_runtime.h>
#include <hip/hip_bf16.h>

// Problem constants (MoEAdaptorLayer_111669150283)
#define BATCH   512
#define LSEQ    50
#define DIN     768
#define DOUT    300
#define NEXP    8
#define NTOK    (BATCH * LSEQ)      // 25600

typedef __bf16 bf16_t;
typedef __attribute__((ext_vector_type(8))) __bf16 bf16x8;
typedef __attribute__((ext_vector_type(4))) float f32x4;

// async global->LDS, 16 B per lane, dst = wave-uniform base + lane*16
#define GLDS16(g, l) __builtin_amdgcn_global_load_lds( \
    (__attribute__((address_space(1))) void*)(g), \
    (__attribute__((address_space(3))) void*)(l), 16, 0, 0)

static __device__ __forceinline__ unsigned short f2bf(float f) {
    unsigned u = __float_as_uint(f);
    u = (u + 0x7fff + ((u >> 16) & 1)) >> 16;   // round-to-nearest-even
    return (unsigned short)u;
}

// ---------------------------------------------------------------------------
// Kernel 1 (fused): xb = bf16(x)  AND  gates = softmax(x @ w_gate).
// One wave per token (verified round 3).
// ---------------------------------------------------------------------------
__global__ __launch_bounds__(256) void cvt_gates_kernel(
    const float* __restrict__ x, const float* __restrict__ wg,
    unsigned short* __restrict__ xb, float* __restrict__ gates)
{
    int t    = blockIdx.x * 4 + (threadIdx.x >> 6);
    int lane = threadIdx.x & 63;
    const float4* xr = (const float4*)(x + (size_t)t * DIN);   // 192 float4/row
    ushort4* xo = (ushort4*)(xb + (size_t)t * DIN);

    float acc[NEXP];
    #pragma unroll
    for (int e = 0; e < NEXP; e++) acc[e] = 0.0f;

    #pragma unroll
    for (int k = 0; k < 3; ++k) {
        int i4 = lane + 64 * k;            // float4 index; i = 4*i4
        float4 v = xr[i4];
        ushort4 u;
        u.x = f2bf(v.x); u.y = f2bf(v.y); u.z = f2bf(v.z); u.w = f2bf(v.w);
        xo[i4] = u;
        const float4* wr = (const float4*)(wg + (size_t)i4 * 4 * NEXP);
        float xs[4] = {v.x, v.y, v.z, v.w};
        #pragma unroll
        for (int s = 0; s < 4; ++s) {
            float4 w0 = wr[2 * s];
            float4 w1 = wr[2 * s + 1];
            float xv = xs[s];
            acc[0] += xv * w0.x; acc[1] += xv * w0.y;
            acc[2] += xv * w0.z; acc[3] += xv * w0.w;
            acc[4] += xv * w1.x; acc[5] += xv * w1.y;
            acc[6] += xv * w1.z; acc[7] += xv * w1.w;
        }
    }
    #pragma unroll
    for (int e = 0; e < NEXP; e++) {
        #pragma unroll
        for (int m = 32; m > 0; m >>= 1) acc[e] += __shfl_xor(acc[e], m, 64);
    }
    float mx = acc[0];
    #pragma unroll
    for (int e = 1; e < NEXP; e++) mx = fmaxf(mx, acc[e]);
    float ex[NEXP]; float s = 0.0f;
    #pragma unroll
    for (int e = 0; e < NEXP; e++) { ex[e] = __expf(acc[e] - mx); s += ex[e]; }
    float inv = 1.0f / s;
    if (lane == 0) {
        #pragma unroll
        for (int e = 0; e < NEXP; e++) gates[(size_t)t * NEXP + e] = ex[e] * inv;
    }
}

// ---------------------------------------------------------------------------
// Kernel 2: bw[l,e,o] = sum_i bias[e,l,i] * W[e,o,i]  AND  wb = bf16(W).
// One wave per (e, o, l-half); W row read ONCE into registers (12 floats/
// lane), then 25 bias-row dots. half 0 also emits the bf16 W row.
// 4800 waves -> 1200 blocks. W traffic 7.4 MB, bias ~180 MB L2-resident.
// ---------------------------------------------------------------------------
__global__ __launch_bounds__(256) void bw_cvtw_kernel(
    const float* __restrict__ bias, const float* __restrict__ W,
    float* __restrict__ bw, unsigned short* __restrict__ wb)
{
    int wid  = blockIdx.x * 4 + (threadIdx.x >> 6);   // 0..4799
    int lane = threadIdx.x & 63;
    int half = wid & 1;
    int eo   = wid >> 1;
    int e = eo / DOUT, o = eo % DOUT;

    const float4* wr = (const float4*)(W + ((size_t)e * DOUT + o) * DIN);
    float4 w4[3];
    #pragma unroll
    for (int k = 0; k < 3; ++k) w4[k] = wr[lane + 64 * k];

    if (half == 0) {
        ushort4* wo = (ushort4*)(wb + ((size_t)e * DOUT + o) * DIN);
        #pragma unroll
        for (int k = 0; k < 3; ++k) {
            ushort4 u;
            u.x = f2bf(w4[k].x); u.y = f2bf(w4[k].y);
            u.z = f2bf(w4[k].z); u.w = f2bf(w4[k].w);
            wo[lane + 64 * k] = u;
        }
    }

    int l0 = 25 * half;
    for (int l = l0; l < l0 + 25; ++l) {
        const float4* br = (const float4*)(bias + ((size_t)e * LSEQ + l) * DIN);
        float acc = 0.0f;
        #pragma unroll
        for (int k = 0; k < 3; ++k) {
            float4 b = br[lane + 64 * k];
            acc += b.x * w4[k].x + b.y * w4[k].y + b.z * w4[k].z + b.w * w4[k].w;
        }
        #pragma unroll
        for (int m = 32; m > 0; m >>= 1) acc += __shfl_xor(acc, m, 64);
        if (lane == 0) bw[((size_t)l * NEXP + e) * DOUT + o] = acc;
    }
}

// ---------------------------------------------------------------------------
// Kernel 3: MFMA main GEMM + fused gate-weighted expert reduction.
// Block: 128 tokens x 128 cols (8 experts x 16 outputs). 4 waves, each a
// SQUARE 64x64 tile (4x4 16x16-frags): 8 ds_read_b128 per 16 MFMA (was 10).
// Wave (h = w>>1, c = w&1): rows 64h..64h+63, cols 64c..64c+63 (experts
// 4c..4c+3). Col n -> e = n>>4, o = o0 + (n&15). Lane (m,q) holds experts
// 4c+cf for output o0+m; cross-half combine via LDS partials at epilogue.
// LDS XOR-swizzle at 16B-chunk granularity via permuted global src addrs
// (verified rounds 2-3).
// ---------------------------------------------------------------------------
#define GTM 128            // tokens per block
#define GTO 16             // outputs per block (x 8 experts = 128 cols)
#define GBK 32             // k per iteration (64 B per row)
#define GKIT (DIN / GBK)   // 24

__global__ __launch_bounds__(256) void moe_mfma_kernel(
    const bf16_t* __restrict__ xb, const bf16_t* __restrict__ wb,
    const float* __restrict__ gates, const float* __restrict__ bw,
    float* __restrict__ out)
{
    __shared__ f32x4 ldsv[1056];      // 16896 B: Xs 8K | Ws 8K (+P overlay)
    char* Xs = (char*)ldsv;
    char* Ws = (char*)ldsv + 8192;

    const int tid  = threadIdx.x;
    const int w    = tid >> 6;
    const int lane = tid & 63;
    const int h    = w >> 1;          // row half
    const int c    = w & 1;           // col half (expert group 4c..4c+3)
    const int o0   = blockIdx.x * GTO;
    const int t0   = blockIdx.y * GTM;

    // ---- staging (identical scheme to round 2, verified) ----
    const int srow4 = lane >> 2;                          // 0..15
    const int c16   = 16 * ((lane & 3) ^ ((lane >> 4) & 3));

    const char* xg0 = (const char*)xb + (size_t)(t0 + 32 * w + srow4) * (DIN * 2) + c16;
    const char* xg1 = xg0 + (size_t)16 * (DIN * 2);
    char* xl = Xs + 2048 * w;

    int n0 = 32 * w + srow4;
    int n1 = n0 + 16;
    int e0 = n0 >> 4, oo0 = o0 + (n0 & 15); if (oo0 >= DOUT) oo0 = DOUT - 1;
    int e1 = n1 >> 4, oo1 = o0 + (n1 & 15); if (oo1 >= DOUT) oo1 = DOUT - 1;
    const char* wg0 = (const char*)wb + (size_t)(e0 * DOUT + oo0) * (DIN * 2) + c16;
    const char* wg1 = (const char*)wb + (size_t)(e1 * DOUT + oo1) * (DIN * 2) + c16;
    char* wl = Ws + 2048 * w;

    // ---- fragment read offsets (swizzled) ----
    const int m = lane & 15, q = lane >> 4;
    const int sw = 16 * (q ^ ((m >> 2) & 3));
    int aoff[4], boff[4];
    #pragma unroll
    for (int rf = 0; rf < 4; ++rf) aoff[rf] = 64 * (64 * h + 16 * rf + m) + sw;
    #pragma unroll
    for (int cf = 0; cf < 4; ++cf) boff[cf] = 64 * (64 * c + 16 * cf + m) + sw;

    f32x4 acc[4][4] = {};

    for (int it = 0; it < GKIT; ++it) {
        GLDS16(xg0, xl);
        GLDS16(xg1, xl + 1024);
        GLDS16(wg0, wl);
        GLDS16(wg1, wl + 1024);
        xg0 += 64; xg1 += 64; wg0 += 64; wg1 += 64;
        __syncthreads();

        bf16x8 a[4];
        #pragma unroll
        for (int rf = 0; rf < 4; ++rf) a[rf] = *(const bf16x8*)(Xs + aoff[rf]);
        #pragma unroll
        for (int cf = 0; cf < 4; ++cf) {
            bf16x8 b = *(const bf16x8*)(Ws + boff[cf]);
            #pragma unroll
            for (int rf = 0; rf < 4; ++rf)
                acc[rf][cf] = __builtin_amdgcn_mfma_f32_16x16x32_bf16(a[rf], b, acc[rf][cf], 0, 0, 0);
        }
        __syncthreads();
    }

    // ---- epilogue ----
    // partial over this wave's 4 experts: p[rf][r] for (t, o0+m)
    const int o = o0 + m;
    const bool ovalid = (o < DOUT);
    f32x4 p[4];
    #pragma unroll
    for (int rf = 0; rf < 4; ++rf) {
        #pragma unroll
        for (int r = 0; r < 4; ++r) {
            int t = t0 + 64 * h + 16 * rf + 4 * q + r;
            int l = t % LSEQ;
            float4 g = *(const float4*)(gates + (size_t)t * NEXP + 4 * c);
            float ga[4] = {g.x, g.y, g.z, g.w};
            float s = 0.0f;
            if (ovalid) {
                const float* bp = bw + ((size_t)l * NEXP + 4 * c) * DOUT + o;
                #pragma unroll
                for (int cf = 0; cf < 4; ++cf)
                    s += ga[cf] * (acc[rf][cf][r] - bp[cf * DOUT]);
            }
            p[rf][r] = s;
        }
    }

    // cross-half combine: c=1 waves publish partials, c=0 waves add + store.
    // P[m][tloc] float, row stride 132 (pad to de-phase banks), 8448 B
    // overlaying the (now dead) staging buffers.
    float* P = (float*)ldsv;
    if (c == 1) {
        #pragma unroll
        for (int rf = 0; rf < 4; ++rf)
            *(f32x4*)&P[m * 132 + 64 * h + 16 * rf + 4 * q] = p[rf];
    }
    __syncthreads();
    if (c == 0 && ovalid) {
        #pragma unroll
        for (int rf = 0; rf < 4; ++rf) {
            f32x4 o4 = *(const f32x4*)&P[m * 132 + 64 * h + 16 * rf + 4 * q];
            #pragma unroll
            for (int r = 0; r < 4; ++r) {
                int t = t0 + 64 * h + 16 * rf + 4 * q + r;
                out[(size_t)t * DOUT + o] = p[rf][r] + o4[r];
            }
        }
    }
}

// ---------------------------------------------------------------------------
// Fallback fp32 path (verified round 1) — only if ws too small for bf16 bufs.
// ---------------------------------------------------------------------------
__global__ __launch_bounds__(256) void gates_kernel(
    const float* __restrict__ x, const float* __restrict__ wg,
    float* __restrict__ gates)
{
    int t    = blockIdx.x * 4 + (threadIdx.x >> 6);
    int lane = threadIdx.x & 63;
    const float* xr = x + (size_t)t * DIN;
    float acc[NEXP];
    #pragma unroll
    for (int e = 0; e < NEXP; e++) acc[e] = 0.0f;
    for (int i = lane; i < DIN; i += 64) {
        float xv = xr[i];
        const float* wr = wg + (size_t)i * NEXP;
        #pragma unroll
        for (int e = 0; e < NEXP; e++) acc[e] += xv * wr[e];
    }
    #pragma unroll
    for (int e = 0; e < NEXP; e++) {
        #pragma unroll
        for (int m = 32; m > 0; m >>= 1) acc[e] += __shfl_xor(acc[e], m, 64);
    }
    float mx = acc[0];
    #pragma unroll
    for (int e = 1; e < NEXP; e++) mx = fmaxf(mx, acc[e]);
    float ex[NEXP]; float s = 0.0f;
    #pragma unroll
    for (int e = 0; e < NEXP; e++) { ex[e] = __expf(acc[e] - mx); s += ex[e]; }
    float inv = 1.0f / s;
    if (lane == 0) {
        #pragma unroll
        for (int e = 0; e < NEXP; e++) gates[(size_t)t * NEXP + e] = ex[e] * inv;
    }
}

__global__ __launch_bounds__(256) void bw_kernel(
    const float* __restrict__ bias, const float* __restrict__ W,
    float* __restrict__ bw)
{
    int wave = blockIdx.x * 4 + (threadIdx.x >> 6);
    int lane = threadIdx.x & 63;
    int l   = wave / (NEXP * DOUT);
    int rem = wave % (NEXP * DOUT);
    int e   = rem / DOUT;
    int o   = rem % DOUT;
    const float4* br = (const float4*)(bias + ((size_t)e * LSEQ + l) * DIN);
    const float4* wr = (const float4*)(W    + ((size_t)e * DOUT + o) * DIN);
    float acc = 0.0f;
    #pragma unroll
    for (int k = 0; k < 3; ++k) {
        int i4 = lane + 64 * k;
        float4 b = br[i4], w = wr[i4];
        acc += b.x * w.x + b.y * w.y + b.z * w.z + b.w * w.w;
    }
    #pragma unroll
    for (int m = 32; m > 0; m >>= 1) acc += __shfl_xor(acc, m, 64);
    if (lane == 0) bw[((size_t)l * NEXP + e) * DOUT + o] = acc;
}

#define TM  64
#define TO  16
#define KT  32
#define KTP 36

__global__ __launch_bounds__(256) void moe_main_kernel(
    const float* __restrict__ x, const float* __restrict__ W,
    const float* __restrict__ gates, const float* __restrict__ bw,
    float* __restrict__ out)
{
    __shared__ float Xs[TM][KTP];
    __shared__ float Wls[128][KTP];
    const int tid = threadIdx.x;
    const int t0 = blockIdx.x * TM;
    const int o0 = blockIdx.y * TO;
    const int cg = tid & 15;
    const int tg = tid >> 4;
    const int lrow = tid >> 3;
    const int lk4  = (tid & 7) * 4;
    float acc[4][NEXP];
    #pragma unroll
    for (int i = 0; i < 4; i++)
        #pragma unroll
        for (int j = 0; j < NEXP; j++) acc[i][j] = 0.0f;
    for (int k0 = 0; k0 < DIN; k0 += KT) {
        #pragma unroll
        for (int r = 0; r < 2; r++) {
            int row = lrow + 32 * r;
            float4 v = *(const float4*)&x[((size_t)(t0 + row)) * DIN + k0 + lk4];
            *(float4*)&Xs[row][lk4] = v;
        }
        #pragma unroll
        for (int r = 0; r < 4; r++) {
            int nl = lrow + 32 * r;
            int e  = nl >> 4;
            int o  = o0 + (nl & 15);
            float4 v;
            if (o < DOUT)
                v = *(const float4*)&W[((size_t)e * DOUT + o) * DIN + k0 + lk4];
            else
                v = make_float4(0.f, 0.f, 0.f, 0.f);
            *(float4*)&Wls[nl][lk4] = v;
        }
        __syncthreads();
        #pragma unroll
        for (int k4 = 0; k4 < KT; k4 += 4) {
            float4 xa[4], wb4[NEXP];
            #pragma unroll
            for (int i = 0; i < 4; i++)
                xa[i] = *(const float4*)&Xs[tg + 16 * i][k4];
            #pragma unroll
            for (int j = 0; j < NEXP; j++)
                wb4[j] = *(const float4*)&Wls[cg + 16 * j][k4];
            #pragma unroll
            for (int i = 0; i < 4; i++)
                #pragma unroll
                for (int j = 0; j < NEXP; j++) {
                    acc[i][j] += xa[i].x * wb4[j].x;
                    acc[i][j] += xa[i].y * wb4[j].y;
                    acc[i][j] += xa[i].z * wb4[j].z;
                    acc[i][j] += xa[i].w * wb4[j].w;
                }
        }
        __syncthreads();
    }
    const int o = o0 + cg;
    if (o < DOUT) {
        #pragma unroll
        for (int i = 0; i < 4; i++) {
            int t = t0 + tg + 16 * i;
            int l = t % LSEQ;
            float s = 0.0f;
            #pragma unroll
            for (int j = 0; j < NEXP; j++) {
                float g = gates[(size_t)t * NEXP + j];
                s += g * (acc[i][j] - bw[((size_t)l * NEXP + j) * DOUT + o]);
            }
            out[(size_t)t * DOUT + o] = s;
        }
    }
}

// ---------------------------------------------------------------------------
extern "C" void kernel_launch(void* const* d_in, const int* in_sizes, int n_in,
                              void* d_out, int out_size, void* d_ws, size_t ws_size,
                              hipStream_t stream) {
    const float* x     = (const float*)d_in[0];   // [512,50,768]
    const float* wgate = (const float*)d_in[1];   // [768,8]
    const float* ew    = (const float*)d_in[2];   // [8,300,768]
    const float* ebias = (const float*)d_in[3];   // [8,50,768]
    float* out = (float*)d_out;                   // [512,50,300]

    // ws layout: gates | bw | xb (bf16) | wb (bf16)
    const size_t n_gates = (size_t)NTOK * NEXP;           // 204800 f32
    const size_t n_bw    = (size_t)LSEQ * NEXP * DOUT;    // 120000 f32
    const size_t n_x     = (size_t)NTOK * DIN;            // 19,660,800
    const size_t n_w     = (size_t)NEXP * DOUT * DIN;     // 1,843,200

    float* gates = (float*)d_ws;
    float* bw    = gates + n_gates;
    bf16_t* xb   = (bf16_t*)(bw + n_bw);
    bf16_t* wbuf = xb + n_x;

    const size_t need = (n_gates + n_bw) * 4 + (n_x + n_w) * 2;

    if (ws_size >= need) {
        cvt_gates_kernel<<<NTOK / 4, 256, 0, stream>>>(
            x, wgate, (unsigned short*)xb, gates);
        bw_cvtw_kernel<<<(2 * NEXP * DOUT) / 4, 256, 0, stream>>>(
            ebias, ew, bw, (unsigned short*)wbuf);
        dim3 grid((DOUT + GTO - 1) / GTO, NTOK / GTM);   // 19 x 200
        moe_mfma_kernel<<<grid, 256, 0, stream>>>(xb, wbuf, gates, bw, out);
    } else {
        gates_kernel<<<NTOK / 4, 256, 0, stream>>>(x, wgate, gates);
        bw_kernel<<<(LSEQ * NEXP * DOUT) / 4, 256, 0, stream>>>(ebias, ew, bw);
        dim3 grid(NTOK / TM, (DOUT + TO - 1) / TO);      // 400 x 19
        moe_main_kernel<<<grid, 256, 0, stream>>>(x, ew, gates, bw, out);
    }
}

// Round 5
// 276.991 us; speedup vs baseline: 1.6418x; 1.2524x over previous
//
#include <hip/hip_runtime.h>
#include <hip/hip_bf16.h>

// Problem constants (MoEAdaptorLayer_111669150283)
#define BATCH   512
#define LSEQ    50
#define DIN     768
#define DOUT    300
#define NEXP    8
#define NTOK    (BATCH * LSEQ)      // 25600

typedef __bf16 bf16_t;
typedef __attribute__((ext_vector_type(8))) __bf16 bf16x8;
typedef __attribute__((ext_vector_type(4))) float f32x4;

// async global->LDS, 16 B per lane, dst = wave-uniform base + lane*16
#define GLDS16(g, l) __builtin_amdgcn_global_load_lds( \
    (__attribute__((address_space(1))) void*)(g), \
    (__attribute__((address_space(3))) void*)(l), 16, 0, 0)

static __device__ __forceinline__ unsigned short f2bf(float f) {
    unsigned u = __float_as_uint(f);
    u = (u + 0x7fff + ((u >> 16) & 1)) >> 16;   // round-to-nearest-even
    return (unsigned short)u;
}

// ---------------------------------------------------------------------------
// Kernel 1 (fused): xb = bf16(x)  AND  gates = softmax(x @ w_gate).
// One wave per token, 4 tokens/block. wg staged TRANSPOSED in LDS so the
// GEMV reads are lane-consecutive float4 (round-3/4 version gathered wg
// with 128 B lane stride = 64 lines/instr -> ~150 us; this was the hidden
// helper cost).
// ---------------------------------------------------------------------------
__global__ __launch_bounds__(256) void cvt_gates_kernel(
    const float* __restrict__ x, const float* __restrict__ wg,
    unsigned short* __restrict__ xb, float* __restrict__ gates)
{
    __shared__ float wgT[NEXP][DIN + 4];   // transposed gate weights, padded

    const int tid  = threadIdx.x;
    // stage: 1536 float4 reads of wg (row-major [768][8]) -> wgT[e][i]
    #pragma unroll
    for (int r = 0; r < 6; ++r) {
        int j = tid + 256 * r;             // float4 index 0..1535
        float4 v = ((const float4*)wg)[j];
        int i  = j >> 1;                   // input row 0..767
        int e0 = (j & 1) * 4;              // expert group 0 or 4
        wgT[e0 + 0][i] = v.x;
        wgT[e0 + 1][i] = v.y;
        wgT[e0 + 2][i] = v.z;
        wgT[e0 + 3][i] = v.w;
    }
    __syncthreads();

    int t    = blockIdx.x * 4 + (tid >> 6);
    int lane = tid & 63;
    const float4* xr = (const float4*)(x + (size_t)t * DIN);
    ushort4* xo = (ushort4*)(xb + (size_t)t * DIN);

    float acc[NEXP];
    #pragma unroll
    for (int e = 0; e < NEXP; e++) acc[e] = 0.0f;

    #pragma unroll
    for (int k = 0; k < 3; ++k) {
        int i4 = lane + 64 * k;            // float4 index; i = 4*i4
        float4 v = xr[i4];
        ushort4 u;
        u.x = f2bf(v.x); u.y = f2bf(v.y); u.z = f2bf(v.z); u.w = f2bf(v.w);
        xo[i4] = u;
        #pragma unroll
        for (int e = 0; e < NEXP; ++e) {
            float4 wv = *(const float4*)&wgT[e][4 * i4];
            acc[e] += v.x * wv.x + v.y * wv.y + v.z * wv.z + v.w * wv.w;
        }
    }
    #pragma unroll
    for (int e = 0; e < NEXP; e++) {
        #pragma unroll
        for (int m = 32; m > 0; m >>= 1) acc[e] += __shfl_xor(acc[e], m, 64);
    }
    float mx = acc[0];
    #pragma unroll
    for (int e = 1; e < NEXP; e++) mx = fmaxf(mx, acc[e]);
    float ex[NEXP]; float s = 0.0f;
    #pragma unroll
    for (int e = 0; e < NEXP; e++) { ex[e] = __expf(acc[e] - mx); s += ex[e]; }
    float inv = 1.0f / s;
    if (lane == 0) {
        #pragma unroll
        for (int e = 0; e < NEXP; e++) gates[(size_t)t * NEXP + e] = ex[e] * inv;
    }
}

// ---------------------------------------------------------------------------
// Kernel 2: bw[l,e,o] = sum_i bias[e,l,i] * W[e,o,i]  AND  wb = bf16(W).
// One wave per (e, o, l-half); W row read once into registers. (round 4)
// ---------------------------------------------------------------------------
__global__ __launch_bounds__(256) void bw_cvtw_kernel(
    const float* __restrict__ bias, const float* __restrict__ W,
    float* __restrict__ bw, unsigned short* __restrict__ wb)
{
    int wid  = blockIdx.x * 4 + (threadIdx.x >> 6);   // 0..4799
    int lane = threadIdx.x & 63;
    int half = wid & 1;
    int eo   = wid >> 1;
    int e = eo / DOUT, o = eo % DOUT;

    const float4* wr = (const float4*)(W + ((size_t)e * DOUT + o) * DIN);
    float4 w4[3];
    #pragma unroll
    for (int k = 0; k < 3; ++k) w4[k] = wr[lane + 64 * k];

    if (half == 0) {
        ushort4* wo = (ushort4*)(wb + ((size_t)e * DOUT + o) * DIN);
        #pragma unroll
        for (int k = 0; k < 3; ++k) {
            ushort4 u;
            u.x = f2bf(w4[k].x); u.y = f2bf(w4[k].y);
            u.z = f2bf(w4[k].z); u.w = f2bf(w4[k].w);
            wo[lane + 64 * k] = u;
        }
    }

    int l0 = 25 * half;
    for (int l = l0; l < l0 + 25; ++l) {
        const float4* br = (const float4*)(bias + ((size_t)e * LSEQ + l) * DIN);
        float acc = 0.0f;
        #pragma unroll
        for (int k = 0; k < 3; ++k) {
            float4 b = br[lane + 64 * k];
            acc += b.x * w4[k].x + b.y * w4[k].y + b.z * w4[k].z + b.w * w4[k].w;
        }
        #pragma unroll
        for (int m = 32; m > 0; m >>= 1) acc += __shfl_xor(acc, m, 64);
        if (lane == 0) bw[((size_t)l * NEXP + e) * DOUT + o] = acc;
    }
}

// ---------------------------------------------------------------------------
// Kernel 3: MFMA main GEMM + fused gate-weighted expert reduction.
// Block: 256 tokens x 128 cols (8 experts x 16 outputs). 4 waves, each a
// 64x128 tile (4 rf x 8 cf of 16x16 frags): 12 ds_read_b128 per 32 MFMA
// (was 8 per 16) -> ~1.9x better LDS:MFMA ratio. Wave covers ALL 8 experts,
// so the expert reduction is fully lane-local (no cross-wave combine).
// Col n -> e = n>>4, o = o0 + (n&15). LDS XOR-swizzle at 16B-chunk
// granularity via permuted global src addrs (verified rounds 2-4).
// ---------------------------------------------------------------------------
#define GTM 256            // tokens per block
#define GTO 16             // outputs per block (x 8 experts = 128 cols)
#define GBK 32             // k per iteration (64 B per row)
#define GKIT (DIN / GBK)   // 24

__global__ __launch_bounds__(256, 2) void moe_mfma_kernel(
    const bf16_t* __restrict__ xb, const bf16_t* __restrict__ wb,
    const float* __restrict__ gates, const float* __restrict__ bw,
    float* __restrict__ out)
{
    __shared__ f32x4 ldsv[1536];      // 24576 B: Xs 16K | Ws 8K
    char* Xs = (char*)ldsv;
    char* Ws = (char*)ldsv + 16384;

    const int tid  = threadIdx.x;
    const int w    = tid >> 6;
    const int lane = tid & 63;
    const int o0   = blockIdx.x * GTO;
    const int t0   = blockIdx.y * GTM;

    // ---- staging (swizzle scheme verified rounds 2-4) ----
    const int srow4 = lane >> 2;                          // 0..15
    const int c16   = 16 * ((lane & 3) ^ ((lane >> 4) & 3));

    // X: wave w stages token rows 64w..64w+63 (4 instrs of 16 rows)
    const char* xg[4];
    #pragma unroll
    for (int j = 0; j < 4; ++j)
        xg[j] = (const char*)xb + (size_t)(t0 + 64 * w + 16 * j + srow4) * (DIN * 2) + c16;
    char* xl = Xs + 4096 * w;

    // W: wave w stages col rows 32w..32w+31 (2 instrs of 16)
    const char* wg[2];
    #pragma unroll
    for (int j = 0; j < 2; ++j) {
        int n = 32 * w + 16 * j + srow4;
        int e = n >> 4;
        int o = o0 + (n & 15); if (o >= DOUT) o = DOUT - 1;  // clamp; guarded at store
        wg[j] = (const char*)wb + (size_t)(e * DOUT + o) * (DIN * 2) + c16;
    }
    char* wl = Ws + 2048 * w;

    // ---- fragment read offsets (swizzled) ----
    const int m = lane & 15, q = lane >> 4;
    const int sw = 16 * (q ^ ((m >> 2) & 3));
    int aoff[4], boff[8];
    #pragma unroll
    for (int rf = 0; rf < 4; ++rf) aoff[rf] = 64 * (64 * w + 16 * rf + m) + sw;
    #pragma unroll
    for (int cf = 0; cf < 8; ++cf) boff[cf] = 64 * (16 * cf + m) + sw;

    f32x4 acc[4][8] = {};

    for (int it = 0; it < GKIT; ++it) {
        #pragma unroll
        for (int j = 0; j < 4; ++j) GLDS16(xg[j], xl + 1024 * j);
        #pragma unroll
        for (int j = 0; j < 2; ++j) GLDS16(wg[j], wl + 1024 * j);
        #pragma unroll
        for (int j = 0; j < 4; ++j) xg[j] += 64;
        #pragma unroll
        for (int j = 0; j < 2; ++j) wg[j] += 64;
        __syncthreads();

        bf16x8 a[4];
        #pragma unroll
        for (int rf = 0; rf < 4; ++rf) a[rf] = *(const bf16x8*)(Xs + aoff[rf]);
        #pragma unroll
        for (int cf = 0; cf < 8; ++cf) {
            bf16x8 b = *(const bf16x8*)(Ws + boff[cf]);
            #pragma unroll
            for (int rf = 0; rf < 4; ++rf)
                acc[rf][cf] = __builtin_amdgcn_mfma_f32_16x16x32_bf16(a[rf], b, acc[rf][cf], 0, 0, 0);
        }
        __syncthreads();
    }

    // ---- epilogue: out[t,o] = sum_e g[t,e] * (acc - bw[l,e,o]) ----
    const int o = o0 + m;
    if (o < DOUT) {
        #pragma unroll
        for (int rf = 0; rf < 4; ++rf) {
            #pragma unroll
            for (int r = 0; r < 4; ++r) {
                int t = t0 + 64 * w + 16 * rf + 4 * q + r;
                int l = t % LSEQ;
                float4 g0 = *(const float4*)(gates + (size_t)t * NEXP);
                float4 g1 = *(const float4*)(gates + (size_t)t * NEXP + 4);
                const float* bp = bw + (size_t)l * NEXP * DOUT + o;
                float s = 0.0f;
                s += g0.x * (acc[rf][0][r] - bp[0 * DOUT]);
                s += g0.y * (acc[rf][1][r] - bp[1 * DOUT]);
                s += g0.z * (acc[rf][2][r] - bp[2 * DOUT]);
                s += g0.w * (acc[rf][3][r] - bp[3 * DOUT]);
                s += g1.x * (acc[rf][4][r] - bp[4 * DOUT]);
                s += g1.y * (acc[rf][5][r] - bp[5 * DOUT]);
                s += g1.z * (acc[rf][6][r] - bp[6 * DOUT]);
                s += g1.w * (acc[rf][7][r] - bp[7 * DOUT]);
                out[(size_t)t * DOUT + o] = s;
            }
        }
    }
}

// ---------------------------------------------------------------------------
// Fallback fp32 path (verified round 1) — only if ws too small for bf16 bufs.
// ---------------------------------------------------------------------------
__global__ __launch_bounds__(256) void gates_kernel(
    const float* __restrict__ x, const float* __restrict__ wg,
    float* __restrict__ gates)
{
    int t    = blockIdx.x * 4 + (threadIdx.x >> 6);
    int lane = threadIdx.x & 63;
    const float* xr = x + (size_t)t * DIN;
    float acc[NEXP];
    #pragma unroll
    for (int e = 0; e < NEXP; e++) acc[e] = 0.0f;
    for (int i = lane; i < DIN; i += 64) {
        float xv = xr[i];
        const float* wr = wg + (size_t)i * NEXP;
        #pragma unroll
        for (int e = 0; e < NEXP; e++) acc[e] += xv * wr[e];
    }
    #pragma unroll
    for (int e = 0; e < NEXP; e++) {
        #pragma unroll
        for (int m = 32; m > 0; m >>= 1) acc[e] += __shfl_xor(acc[e], m, 64);
    }
    float mx = acc[0];
    #pragma unroll
    for (int e = 1; e < NEXP; e++) mx = fmaxf(mx, acc[e]);
    float ex[NEXP]; float s = 0.0f;
    #pragma unroll
    for (int e = 0; e < NEXP; e++) { ex[e] = __expf(acc[e] - mx); s += ex[e]; }
    float inv = 1.0f / s;
    if (lane == 0) {
        #pragma unroll
        for (int e = 0; e < NEXP; e++) gates[(size_t)t * NEXP + e] = ex[e] * inv;
    }
}

__global__ __launch_bounds__(256) void bw_kernel(
    const float* __restrict__ bias, const float* __restrict__ W,
    float* __restrict__ bw)
{
    int wave = blockIdx.x * 4 + (threadIdx.x >> 6);
    int lane = threadIdx.x & 63;
    int l   = wave / (NEXP * DOUT);
    int rem = wave % (NEXP * DOUT);
    int e   = rem / DOUT;
    int o   = rem % DOUT;
    const float4* br = (const float4*)(bias + ((size_t)e * LSEQ + l) * DIN);
    const float4* wr = (const float4*)(W    + ((size_t)e * DOUT + o) * DIN);
    float acc = 0.0f;
    #pragma unroll
    for (int k = 0; k < 3; ++k) {
        int i4 = lane + 64 * k;
        float4 b = br[i4], w = wr[i4];
        acc += b.x * w.x + b.y * w.y + b.z * w.z + b.w * w.w;
    }
    #pragma unroll
    for (int m = 32; m > 0; m >>= 1) acc += __shfl_xor(acc, m, 64);
    if (lane == 0) bw[((size_t)l * NEXP + e) * DOUT + o] = acc;
}

#define TM  64
#define TO  16
#define KT  32
#define KTP 36

__global__ __launch_bounds__(256) void moe_main_kernel(
    const float* __restrict__ x, const float* __restrict__ W,
    const float* __restrict__ gates, const float* __restrict__ bw,
    float* __restrict__ out)
{
    __shared__ float Xs[TM][KTP];
    __shared__ float Wls[128][KTP];
    const int tid = threadIdx.x;
    const int t0 = blockIdx.x * TM;
    const int o0 = blockIdx.y * TO;
    const int cg = tid & 15;
    const int tg = tid >> 4;
    const int lrow = tid >> 3;
    const int lk4  = (tid & 7) * 4;
    float acc[4][NEXP];
    #pragma unroll
    for (int i = 0; i < 4; i++)
        #pragma unroll
        for (int j = 0; j < NEXP; j++) acc[i][j] = 0.0f;
    for (int k0 = 0; k0 < DIN; k0 += KT) {
        #pragma unroll
        for (int r = 0; r < 2; r++) {
            int row = lrow + 32 * r;
            float4 v = *(const float4*)&x[((size_t)(t0 + row)) * DIN + k0 + lk4];
            *(float4*)&Xs[row][lk4] = v;
        }
        #pragma unroll
        for (int r = 0; r < 4; r++) {
            int nl = lrow + 32 * r;
            int e  = nl >> 4;
            int o  = o0 + (nl & 15);
            float4 v;
            if (o < DOUT)
                v = *(const float4*)&W[((size_t)e * DOUT + o) * DIN + k0 + lk4];
            else
                v = make_float4(0.f, 0.f, 0.f, 0.f);
            *(float4*)&Wls[nl][lk4] = v;
        }
        __syncthreads();
        #pragma unroll
        for (int k4 = 0; k4 < KT; k4 += 4) {
            float4 xa[4], wb4[NEXP];
            #pragma unroll
            for (int i = 0; i < 4; i++)
                xa[i] = *(const float4*)&Xs[tg + 16 * i][k4];
            #pragma unroll
            for (int j = 0; j < NEXP; j++)
                wb4[j] = *(const float4*)&Wls[cg + 16 * j][k4];
            #pragma unroll
            for (int i = 0; i < 4; i++)
                #pragma unroll
                for (int j = 0; j < NEXP; j++) {
                    acc[i][j] += xa[i].x * wb4[j].x;
                    acc[i][j] += xa[i].y * wb4[j].y;
                    acc[i][j] += xa[i].z * wb4[j].z;
                    acc[i][j] += xa[i].w * wb4[j].w;
                }
        }
        __syncthreads();
    }
    const int o = o0 + cg;
    if (o < DOUT) {
        #pragma unroll
        for (int i = 0; i < 4; i++) {
            int t = t0 + tg + 16 * i;
            int l = t % LSEQ;
            float s = 0.0f;
            #pragma unroll
            for (int j = 0; j < NEXP; j++) {
                float g = gates[(size_t)t * NEXP + j];
                s += g * (acc[i][j] - bw[((size_t)l * NEXP + j) * DOUT + o]);
            }
            out[(size_t)t * DOUT + o] = s;
        }
    }
}

// ---------------------------------------------------------------------------
extern "C" void kernel_launch(void* const* d_in, const int* in_sizes, int n_in,
                              void* d_out, int out_size, void* d_ws, size_t ws_size,
                              hipStream_t stream) {
    const float* x     = (const float*)d_in[0];   // [512,50,768]
    const float* wgate = (const float*)d_in[1];   // [768,8]
    const float* ew    = (const float*)d_in[2];   // [8,300,768]
    const float* ebias = (const float*)d_in[3];   // [8,50,768]
    float* out = (float*)d_out;                   // [512,50,300]

    // ws layout: gates | bw | xb (bf16) | wb (bf16)
    const size_t n_gates = (size_t)NTOK * NEXP;           // 204800 f32
    const size_t n_bw    = (size_t)LSEQ * NEXP * DOUT;    // 120000 f32
    const size_t n_x     = (size_t)NTOK * DIN;            // 19,660,800
    const size_t n_w     = (size_t)NEXP * DOUT * DIN;     // 1,843,200

    float* gates = (float*)d_ws;
    float* bw    = gates + n_gates;
    bf16_t* xb   = (bf16_t*)(bw + n_bw);
    bf16_t* wbuf = xb + n_x;

    const size_t need = (n_gates + n_bw) * 4 + (n_x + n_w) * 2;

    if (ws_size >= need) {
        cvt_gates_kernel<<<NTOK / 4, 256, 0, stream>>>(
            x, wgate, (unsigned short*)xb, gates);
        bw_cvtw_kernel<<<(2 * NEXP * DOUT) / 4, 256, 0, stream>>>(
            ebias, ew, bw, (unsigned short*)wbuf);
        dim3 grid((DOUT + GTO - 1) / GTO, NTOK / GTM);   // 19 x 100
        moe_mfma_kernel<<<grid, 256, 0, stream>>>(xb, wbuf, gates, bw, out);
    } else {
        gates_kernel<<<NTOK / 4, 256, 0, stream>>>(x, wgate, gates);
        bw_kernel<<<(LSEQ * NEXP * DOUT) / 4, 256, 0, stream>>>(ebias, ew, bw);
        dim3 grid(NTOK / TM, (DOUT + TO - 1) / TO);      // 400 x 19
        moe_main_kernel<<<grid, 256, 0, stream>>>(x, ew, gates, bw, out);
    }
}

// Round 6
// 270.434 us; speedup vs baseline: 1.6816x; 1.0242x over previous
//
#include <hip/hip_runtime.h>
#include <hip/hip_bf16.h>

// Problem constants (MoEAdaptorLayer_111669150283)
#define BATCH   512
#define LSEQ    50
#define DIN     768
#define DOUT    300
#define NEXP    8
#define NTOK    (BATCH * LSEQ)      // 25600

typedef __bf16 bf16_t;
typedef __attribute__((ext_vector_type(8))) __bf16 bf16x8;
typedef __attribute__((ext_vector_type(4))) float f32x4;

// async global->LDS, 16 B per lane, dst = wave-uniform base + lane*16
#define GLDS16(g, l) __builtin_amdgcn_global_load_lds( \
    (__attribute__((address_space(1))) void*)(g), \
    (__attribute__((address_space(3))) void*)(l), 16, 0, 0)

static __device__ __forceinline__ unsigned short f2bf(float f) {
    unsigned u = __float_as_uint(f);
    u = (u + 0x7fff + ((u >> 16) & 1)) >> 16;   // round-to-nearest-even
    return (unsigned short)u;
}

// ---------------------------------------------------------------------------
// Kernel 1 (merged prep): block-range split.
//   blocks [0, 6400):    xb = bf16(x), gates = softmax(x @ w_gate)
//   blocks [6400, 7600): bw[l,e,o] = <bias[e,l,:], W[e,o,:]>, wb = bf16(W)
// Merged so the two independent phases run concurrently (they were stream-
// serialized as separate launches) and one launch is removed.
// ---------------------------------------------------------------------------
#define PREP_GATE_BLOCKS (NTOK / 4)              // 6400
#define PREP_BW_BLOCKS   ((2 * NEXP * DOUT) / 4) // 1200

__global__ __launch_bounds__(256) void prep_kernel(
    const float* __restrict__ x, const float* __restrict__ wg,
    const float* __restrict__ bias, const float* __restrict__ W,
    unsigned short* __restrict__ xb, float* __restrict__ gates,
    float* __restrict__ bw, unsigned short* __restrict__ wb)
{
    const int tid  = threadIdx.x;
    const int lane = tid & 63;

    if (blockIdx.x < PREP_GATE_BLOCKS) {
        // ---- gates + x conversion (verified round 5) ----
        __shared__ float wgT[NEXP][DIN + 4];   // transposed gate weights
        #pragma unroll
        for (int r = 0; r < 6; ++r) {
            int j = tid + 256 * r;             // float4 index 0..1535
            float4 v = ((const float4*)wg)[j];
            int i  = j >> 1;
            int e0 = (j & 1) * 4;
            wgT[e0 + 0][i] = v.x;
            wgT[e0 + 1][i] = v.y;
            wgT[e0 + 2][i] = v.z;
            wgT[e0 + 3][i] = v.w;
        }
        __syncthreads();

        int t = blockIdx.x * 4 + (tid >> 6);
        const float4* xr = (const float4*)(x + (size_t)t * DIN);
        ushort4* xo = (ushort4*)(xb + (size_t)t * DIN);

        float acc[NEXP];
        #pragma unroll
        for (int e = 0; e < NEXP; e++) acc[e] = 0.0f;

        #pragma unroll
        for (int k = 0; k < 3; ++k) {
            int i4 = lane + 64 * k;
            float4 v = xr[i4];
            ushort4 u;
            u.x = f2bf(v.x); u.y = f2bf(v.y); u.z = f2bf(v.z); u.w = f2bf(v.w);
            xo[i4] = u;
            #pragma unroll
            for (int e = 0; e < NEXP; ++e) {
                float4 wv = *(const float4*)&wgT[e][4 * i4];
                acc[e] += v.x * wv.x + v.y * wv.y + v.z * wv.z + v.w * wv.w;
            }
        }
        #pragma unroll
        for (int e = 0; e < NEXP; e++) {
            #pragma unroll
            for (int m = 32; m > 0; m >>= 1) acc[e] += __shfl_xor(acc[e], m, 64);
        }
        float mx = acc[0];
        #pragma unroll
        for (int e = 1; e < NEXP; e++) mx = fmaxf(mx, acc[e]);
        float ex[NEXP]; float s = 0.0f;
        #pragma unroll
        for (int e = 0; e < NEXP; e++) { ex[e] = __expf(acc[e] - mx); s += ex[e]; }
        float inv = 1.0f / s;
        if (lane == 0) {
            #pragma unroll
            for (int e = 0; e < NEXP; e++) gates[(size_t)t * NEXP + e] = ex[e] * inv;
        }
    } else {
        // ---- bw + W conversion (verified round 4) ----
        int wid  = (blockIdx.x - PREP_GATE_BLOCKS) * 4 + (tid >> 6);  // 0..4799
        int half = wid & 1;
        int eo   = wid >> 1;
        int e = eo / DOUT, o = eo % DOUT;

        const float4* wr = (const float4*)(W + ((size_t)e * DOUT + o) * DIN);
        float4 w4[3];
        #pragma unroll
        for (int k = 0; k < 3; ++k) w4[k] = wr[lane + 64 * k];

        if (half == 0) {
            ushort4* wo = (ushort4*)(wb + ((size_t)e * DOUT + o) * DIN);
            #pragma unroll
            for (int k = 0; k < 3; ++k) {
                ushort4 u;
                u.x = f2bf(w4[k].x); u.y = f2bf(w4[k].y);
                u.z = f2bf(w4[k].z); u.w = f2bf(w4[k].w);
                wo[lane + 64 * k] = u;
            }
        }

        int l0 = 25 * half;
        for (int l = l0; l < l0 + 25; ++l) {
            const float4* br = (const float4*)(bias + ((size_t)e * LSEQ + l) * DIN);
            float acc = 0.0f;
            #pragma unroll
            for (int k = 0; k < 3; ++k) {
                float4 b = br[lane + 64 * k];
                acc += b.x * w4[k].x + b.y * w4[k].y + b.z * w4[k].z + b.w * w4[k].w;
            }
            #pragma unroll
            for (int m = 32; m > 0; m >>= 1) acc += __shfl_xor(acc, m, 64);
            if (lane == 0) bw[((size_t)l * NEXP + e) * DOUT + o] = acc;
        }
    }
}

// ---------------------------------------------------------------------------
// Kernel 2: MFMA main GEMM + fused gate-weighted expert reduction.
// Geometry as round 5 (proven): block 256 tokens x 128 cols, 4 waves of
// 64x128 (4rf x 8cf). LDS-read-bound at MfmaUtil~29% (model-validated).
// NEW: XCD-aware linear grid. bid%8 = XCD; each XCD owns a contiguous group
// of 13 row-tiles x all 19 o-tiles (o fastest), so an X-tile is fetched into
// exactly one XCD L2 and reused by its 19 o-blocks (~1.3 MB working set).
// ---------------------------------------------------------------------------
#define GTM 256            // tokens per block
#define GTO 16             // outputs per block (x 8 experts = 128 cols)
#define GBK 32             // k per iteration
#define GKIT (DIN / GBK)   // 24
#define NRT  (NTOK / GTM)  // 100 row tiles
#define NOT  19            // o tiles
#define RPG  13            // row-tiles per XCD group (8*13=104 >= 100)

__global__ __launch_bounds__(256, 2) void moe_mfma_kernel(
    const bf16_t* __restrict__ xb, const bf16_t* __restrict__ wb,
    const float* __restrict__ gates, const float* __restrict__ bw,
    float* __restrict__ out)
{
    // grid decode: bid = slot*8 + g; slot = r_in*19 + o_t; r_t = g*13 + r_in
    const int bid  = blockIdx.x;
    const int g    = bid & 7;
    const int slot = bid >> 3;
    const int r_in = slot / NOT;
    const int o_t  = slot - NOT * r_in;
    const int r_t  = g * RPG + r_in;
    if (r_t >= NRT) return;            // uniform early-exit (before any barrier)
    const int o0 = o_t * GTO;
    const int t0 = r_t * GTM;

    __shared__ f32x4 ldsv[1536];      // 24576 B: Xs 16K | Ws 8K
    char* Xs = (char*)ldsv;
    char* Ws = (char*)ldsv + 16384;

    const int tid  = threadIdx.x;
    const int w    = tid >> 6;
    const int lane = tid & 63;

    // ---- staging (swizzle scheme verified rounds 2-5) ----
    const int srow4 = lane >> 2;                          // 0..15
    const int c16   = 16 * ((lane & 3) ^ ((lane >> 4) & 3));

    const char* xg[4];
    #pragma unroll
    for (int j = 0; j < 4; ++j)
        xg[j] = (const char*)xb + (size_t)(t0 + 64 * w + 16 * j + srow4) * (DIN * 2) + c16;
    char* xl = Xs + 4096 * w;

    const char* wg[2];
    #pragma unroll
    for (int j = 0; j < 2; ++j) {
        int n = 32 * w + 16 * j + srow4;
        int e = n >> 4;
        int o = o0 + (n & 15); if (o >= DOUT) o = DOUT - 1;  // clamp; guarded at store
        wg[j] = (const char*)wb + (size_t)(e * DOUT + o) * (DIN * 2) + c16;
    }
    char* wl = Ws + 2048 * w;

    // ---- fragment read offsets (swizzled) ----
    const int m = lane & 15, q = lane >> 4;
    const int sw = 16 * (q ^ ((m >> 2) & 3));
    int aoff[4], boff[8];
    #pragma unroll
    for (int rf = 0; rf < 4; ++rf) aoff[rf] = 64 * (64 * w + 16 * rf + m) + sw;
    #pragma unroll
    for (int cf = 0; cf < 8; ++cf) boff[cf] = 64 * (16 * cf + m) + sw;

    f32x4 acc[4][8] = {};

    for (int it = 0; it < GKIT; ++it) {
        #pragma unroll
        for (int j = 0; j < 4; ++j) GLDS16(xg[j], xl + 1024 * j);
        #pragma unroll
        for (int j = 0; j < 2; ++j) GLDS16(wg[j], wl + 1024 * j);
        #pragma unroll
        for (int j = 0; j < 4; ++j) xg[j] += 64;
        #pragma unroll
        for (int j = 0; j < 2; ++j) wg[j] += 64;
        __syncthreads();

        bf16x8 a[4];
        #pragma unroll
        for (int rf = 0; rf < 4; ++rf) a[rf] = *(const bf16x8*)(Xs + aoff[rf]);
        #pragma unroll
        for (int cf = 0; cf < 8; ++cf) {
            bf16x8 b = *(const bf16x8*)(Ws + boff[cf]);
            #pragma unroll
            for (int rf = 0; rf < 4; ++rf)
                acc[rf][cf] = __builtin_amdgcn_mfma_f32_16x16x32_bf16(a[rf], b, acc[rf][cf], 0, 0, 0);
        }
        __syncthreads();
    }

    // ---- epilogue: out[t,o] = sum_e g[t,e] * (acc - bw[l,e,o]) ----
    const int o = o0 + m;
    if (o < DOUT) {
        #pragma unroll
        for (int rf = 0; rf < 4; ++rf) {
            #pragma unroll
            for (int r = 0; r < 4; ++r) {
                int t = t0 + 64 * w + 16 * rf + 4 * q + r;
                int l = t % LSEQ;
                float4 g0 = *(const float4*)(gates + (size_t)t * NEXP);
                float4 g1 = *(const float4*)(gates + (size_t)t * NEXP + 4);
                const float* bp = bw + (size_t)l * NEXP * DOUT + o;
                float s = 0.0f;
                s += g0.x * (acc[rf][0][r] - bp[0 * DOUT]);
                s += g0.y * (acc[rf][1][r] - bp[1 * DOUT]);
                s += g0.z * (acc[rf][2][r] - bp[2 * DOUT]);
                s += g0.w * (acc[rf][3][r] - bp[3 * DOUT]);
                s += g1.x * (acc[rf][4][r] - bp[4 * DOUT]);
                s += g1.y * (acc[rf][5][r] - bp[5 * DOUT]);
                s += g1.z * (acc[rf][6][r] - bp[6 * DOUT]);
                s += g1.w * (acc[rf][7][r] - bp[7 * DOUT]);
                out[(size_t)t * DOUT + o] = s;
            }
        }
    }
}

// ---------------------------------------------------------------------------
// Fallback fp32 path (verified round 1) — only if ws too small for bf16 bufs.
// ---------------------------------------------------------------------------
__global__ __launch_bounds__(256) void gates_kernel(
    const float* __restrict__ x, const float* __restrict__ wg,
    float* __restrict__ gates)
{
    int t    = blockIdx.x * 4 + (threadIdx.x >> 6);
    int lane = threadIdx.x & 63;
    const float* xr = x + (size_t)t * DIN;
    float acc[NEXP];
    #pragma unroll
    for (int e = 0; e < NEXP; e++) acc[e] = 0.0f;
    for (int i = lane; i < DIN; i += 64) {
        float xv = xr[i];
        const float* wr = wg + (size_t)i * NEXP;
        #pragma unroll
        for (int e = 0; e < NEXP; e++) acc[e] += xv * wr[e];
    }
    #pragma unroll
    for (int e = 0; e < NEXP; e++) {
        #pragma unroll
        for (int m = 32; m > 0; m >>= 1) acc[e] += __shfl_xor(acc[e], m, 64);
    }
    float mx = acc[0];
    #pragma unroll
    for (int e = 1; e < NEXP; e++) mx = fmaxf(mx, acc[e]);
    float ex[NEXP]; float s = 0.0f;
    #pragma unroll
    for (int e = 0; e < NEXP; e++) { ex[e] = __expf(acc[e] - mx); s += ex[e]; }
    float inv = 1.0f / s;
    if (lane == 0) {
        #pragma unroll
        for (int e = 0; e < NEXP; e++) gates[(size_t)t * NEXP + e] = ex[e] * inv;
    }
}

__global__ __launch_bounds__(256) void bw_kernel(
    const float* __restrict__ bias, const float* __restrict__ W,
    float* __restrict__ bw)
{
    int wave = blockIdx.x * 4 + (threadIdx.x >> 6);
    int lane = threadIdx.x & 63;
    int l   = wave / (NEXP * DOUT);
    int rem = wave % (NEXP * DOUT);
    int e   = rem / DOUT;
    int o   = rem % DOUT;
    const float4* br = (const float4*)(bias + ((size_t)e * LSEQ + l) * DIN);
    const float4* wr = (const float4*)(W    + ((size_t)e * DOUT + o) * DIN);
    float acc = 0.0f;
    #pragma unroll
    for (int k = 0; k < 3; ++k) {
        int i4 = lane + 64 * k;
        float4 b = br[i4], w = wr[i4];
        acc += b.x * w.x + b.y * w.y + b.z * w.z + b.w * w.w;
    }
    #pragma unroll
    for (int m = 32; m > 0; m >>= 1) acc += __shfl_xor(acc, m, 64);
    if (lane == 0) bw[((size_t)l * NEXP + e) * DOUT + o] = acc;
}

#define TM  64
#define TO  16
#define KT  32
#define KTP 36

__global__ __launch_bounds__(256) void moe_main_kernel(
    const float* __restrict__ x, const float* __restrict__ W,
    const float* __restrict__ gates, const float* __restrict__ bw,
    float* __restrict__ out)
{
    __shared__ float Xs[TM][KTP];
    __shared__ float Wls[128][KTP];
    const int tid = threadIdx.x;
    const int t0 = blockIdx.x * TM;
    const int o0 = blockIdx.y * TO;
    const int cg = tid & 15;
    const int tg = tid >> 4;
    const int lrow = tid >> 3;
    const int lk4  = (tid & 7) * 4;
    float acc[4][NEXP];
    #pragma unroll
    for (int i = 0; i < 4; i++)
        #pragma unroll
        for (int j = 0; j < NEXP; j++) acc[i][j] = 0.0f;
    for (int k0 = 0; k0 < DIN; k0 += KT) {
        #pragma unroll
        for (int r = 0; r < 2; r++) {
            int row = lrow + 32 * r;
            float4 v = *(const float4*)&x[((size_t)(t0 + row)) * DIN + k0 + lk4];
            *(float4*)&Xs[row][lk4] = v;
        }
        #pragma unroll
        for (int r = 0; r < 4; r++) {
            int nl = lrow + 32 * r;
            int e  = nl >> 4;
            int o  = o0 + (nl & 15);
            float4 v;
            if (o < DOUT)
                v = *(const float4*)&W[((size_t)e * DOUT + o) * DIN + k0 + lk4];
            else
                v = make_float4(0.f, 0.f, 0.f, 0.f);
            *(float4*)&Wls[nl][lk4] = v;
        }
        __syncthreads();
        #pragma unroll
        for (int k4 = 0; k4 < KT; k4 += 4) {
            float4 xa[4], wb4[NEXP];
            #pragma unroll
            for (int i = 0; i < 4; i++)
                xa[i] = *(const float4*)&Xs[tg + 16 * i][k4];
            #pragma unroll
            for (int j = 0; j < NEXP; j++)
                wb4[j] = *(const float4*)&Wls[cg + 16 * j][k4];
            #pragma unroll
            for (int i = 0; i < 4; i++)
                #pragma unroll
                for (int j = 0; j < NEXP; j++) {
                    acc[i][j] += xa[i].x * wb4[j].x;
                    acc[i][j] += xa[i].y * wb4[j].y;
                    acc[i][j] += xa[i].z * wb4[j].z;
                    acc[i][j] += xa[i].w * wb4[j].w;
                }
        }
        __syncthreads();
    }
    const int o = o0 + cg;
    if (o < DOUT) {
        #pragma unroll
        for (int i = 0; i < 4; i++) {
            int t = t0 + tg + 16 * i;
            int l = t % LSEQ;
            float s = 0.0f;
            #pragma unroll
            for (int j = 0; j < NEXP; j++) {
                float g = gates[(size_t)t * NEXP + j];
                s += g * (acc[i][j] - bw[((size_t)l * NEXP + j) * DOUT + o]);
            }
            out[(size_t)t * DOUT + o] = s;
        }
    }
}

// ---------------------------------------------------------------------------
extern "C" void kernel_launch(void* const* d_in, const int* in_sizes, int n_in,
                              void* d_out, int out_size, void* d_ws, size_t ws_size,
                              hipStream_t stream) {
    const float* x     = (const float*)d_in[0];   // [512,50,768]
    const float* wgate = (const float*)d_in[1];   // [768,8]
    const float* ew    = (const float*)d_in[2];   // [8,300,768]
    const float* ebias = (const float*)d_in[3];   // [8,50,768]
    float* out = (float*)d_out;                   // [512,50,300]

    // ws layout: gates | bw | xb (bf16) | wb (bf16)
    const size_t n_gates = (size_t)NTOK * NEXP;           // 204800 f32
    const size_t n_bw    = (size_t)LSEQ * NEXP * DOUT;    // 120000 f32
    const size_t n_x     = (size_t)NTOK * DIN;            // 19,660,800
    const size_t n_w     = (size_t)NEXP * DOUT * DIN;     // 1,843,200

    float* gates = (float*)d_ws;
    float* bw    = gates + n_gates;
    bf16_t* xb   = (bf16_t*)(bw + n_bw);
    bf16_t* wbuf = xb + n_x;

    const size_t need = (n_gates + n_bw) * 4 + (n_x + n_w) * 2;

    if (ws_size >= need) {
        prep_kernel<<<PREP_GATE_BLOCKS + PREP_BW_BLOCKS, 256, 0, stream>>>(
            x, wgate, ebias, ew, (unsigned short*)xb, gates, bw, (unsigned short*)wbuf);
        moe_mfma_kernel<<<8 * RPG * NOT, 256, 0, stream>>>(xb, wbuf, gates, bw, out);
    } else {
        gates_kernel<<<NTOK / 4, 256, 0, stream>>>(x, wgate, gates);
        bw_kernel<<<(LSEQ * NEXP * DOUT) / 4, 256, 0, stream>>>(ebias, ew, bw);
        dim3 grid(NTOK / TM, (DOUT + TO - 1) / TO);      // 400 x 19
        moe_main_kernel<<<grid, 256, 0, stream>>>(x, ew, gates, bw, out);
    }
}